// Round 9
// baseline (5169.017 us; speedup 1.0000x reference)
//
#include <hip/hip_runtime.h>
#include <cmath>

// Leaky RNN:  h_t = 0.9 h_{t-1} + 0.1 tanh(h W_hh + u_t W_uh + b_h);  y_t = h_t W_hy + b_y
// B=64, T=2048, N_in=128, N_h=512, N_out=128.
//
// Phase 2 (critical path): one WG per batch row, 512 threads = 8 waves.  Round-8 analysis:
// W-delivery-bound (LDS pipe ~2000cy + L2 ~1750cy per step, VALU 1024 idle-ish).  Fix:
// open the THIRD delivery channel — AGPRs.  gfx950 unified RF: 128 AGPR/thread on top of
// the 128-VGPR pin (256 total @ 2 waves/SIMD, same occupancy).  Lane owns 8 cols x 64 k:
// cols 0-3 in AGPRs (128 a-regs, v_accvgpr_write once, volatile v_accvgpr_read per use —
// volatile prevents loop-invariant hoisting back into VGPRs), cols 4-7 streamed from L2
// (256 KB/step/CU) via 2-group double buffer of 8 named uint4.  NO W in LDS (LDS = h
// broadcast + partials only, ~19.5 KB).  v_dot2_f32_f16, 8 f32 accs, 2 barriers/step.
//
// ws: U (f16 [B*T][512], 128 MiB) | H (f16 [B*T][512], 128 MiB).
// Wpk (512 KiB packed f16 W_hh) lives in d_out (dead until y_gemm runs last).

#define NB 64
#define NT 2048
#define NI 128
#define NH 512
#define NO 128

typedef unsigned short u16;
typedef unsigned int u32;
typedef _Float16 half2_t __attribute__((ext_vector_type(2)));

__device__ __forceinline__ float fdot2(half2_t a, half2_t b, float c) {
#if __has_builtin(__builtin_amdgcn_fdot2)
    return __builtin_amdgcn_fdot2(a, b, c, false);
#else
    return c + (float)a[0] * (float)b[0] + (float)a[1] * (float)b[1];
#endif
}
#define BCH(u) __builtin_bit_cast(half2_t, (u))

__device__ __forceinline__ u16 ftoh(float x) { return __builtin_bit_cast(u16, (_Float16)x); }
__device__ __forceinline__ float htof(u16 x) { return (float)__builtin_bit_cast(_Float16, x); }

__device__ __forceinline__ u32 ldpair(const float* __restrict__ W, int k, int c) {
    half2_t v;
    v[0] = (_Float16)W[(size_t)k * NH + c];
    v[1] = (_Float16)W[(size_t)(k + 1) * NH + c];
    return __builtin_bit_cast(u32, v);
}

// ---------------- Phase 0: pack W_hh to f16 in consumer order ----------------
// Section A (AGPR-resident, idx<16384) and Section S (streamed, idx>=16384), same layout:
// base + w*2048 + (q*4+i)*64 + l;  col = 8l + (sec?4:0) + i;  quad = k-pairs kb+{0,2,4,6},
// kb = 64w + 8q.
__global__ __launch_bounds__(256) void wpack(const float* __restrict__ Whh,
                                             uint4* __restrict__ Wpk) {
    const int idx = blockIdx.x * 256 + threadIdx.x;   // 0..32767
    const int sec = idx >> 14;
    const int r14 = idx & 16383;
    const int w = r14 >> 11;
    const int r = r14 & 2047;
    const int t = r >> 6;             // 0..31
    const int q = t >> 2, i = t & 3;
    const int l = r & 63;
    const int col = 8 * l + (sec ? 4 : 0) + i;
    const int kb = 64 * w + 8 * q;
    uint4 o;
    o.x = ldpair(Whh, kb + 0, col);
    o.y = ldpair(Whh, kb + 2, col);
    o.z = ldpair(Whh, kb + 4, col);
    o.w = ldpair(Whh, kb + 6, col);
    Wpk[idx] = o;
}

// ---------------- Phase 1: U[m][n] = u[m][:] @ W_uh[:,n] + b_h[n]  (f16 out) ----------------
__global__ __launch_bounds__(256) void u_gemm(
        const float* __restrict__ A,    // u  [M][NI]
        const float* __restrict__ Bw,   // W_uh [NI][NH]
        const float* __restrict__ bh,   // [NH]
        u16* __restrict__ C) {          // U [M][NH] f16
    const int n0 = blockIdx.x * 64;
    const int m0 = blockIdx.y * 64;
    const int tid = threadIdx.x;
    const int tn = tid & 15, tm = tid >> 4;
    __shared__ float As[64][68];   // [k][m]
    __shared__ float Bs[64][68];   // [k][n]
    float acc[4][4] = {};
    for (int k0 = 0; k0 < NI; k0 += 64) {
        const int r = tid >> 4, c4 = tid & 15;
        #pragma unroll
        for (int p = 0; p < 4; ++p) {
            const int row = r + p * 16;
            float4 v = *reinterpret_cast<const float4*>(&A[(size_t)(m0 + row) * NI + k0 + c4 * 4]);
            As[c4 * 4 + 0][row] = v.x; As[c4 * 4 + 1][row] = v.y;
            As[c4 * 4 + 2][row] = v.z; As[c4 * 4 + 3][row] = v.w;
        }
        #pragma unroll
        for (int p = 0; p < 4; ++p) {
            const int row = r + p * 16;
            float4 v = *reinterpret_cast<const float4*>(&Bw[(size_t)(k0 + row) * NH + n0 + c4 * 4]);
            *reinterpret_cast<float4*>(&Bs[row][c4 * 4]) = v;
        }
        __syncthreads();
        #pragma unroll
        for (int kk = 0; kk < 64; ++kk) {
            float4 av = *reinterpret_cast<const float4*>(&As[kk][tm * 4]);
            float4 bv = *reinterpret_cast<const float4*>(&Bs[kk][tn * 4]);
            const float am[4] = {av.x, av.y, av.z, av.w};
            const float bn[4] = {bv.x, bv.y, bv.z, bv.w};
            #pragma unroll
            for (int i = 0; i < 4; ++i)
                #pragma unroll
                for (int j = 0; j < 4; ++j)
                    acc[i][j] += am[i] * bn[j];
        }
        __syncthreads();
    }
    float bias[4];
    #pragma unroll
    for (int j = 0; j < 4; ++j) bias[j] = bh[n0 + tn * 4 + j];
    #pragma unroll
    for (int i = 0; i < 4; ++i) {
        const int m = m0 + tm * 4 + i;
        ushort4 out;
        out.x = ftoh(acc[i][0] + bias[0]);
        out.y = ftoh(acc[i][1] + bias[1]);
        out.z = ftoh(acc[i][2] + bias[2]);
        out.w = ftoh(acc[i][3] + bias[3]);
        *reinterpret_cast<ushort4*>(&C[(size_t)m * NH + n0 + tn * 4]) = out;
    }
}

// ---------------- Phase 2: sequential recurrence ----------------
// AGPR machinery: 128 named u32 AGPR-resident W words per thread (cols 8l+0..3).
#define ADECL1(c, q) u32 A##c##_##q##_0, A##c##_##q##_1, A##c##_##q##_2, A##c##_##q##_3;
#define ADECLQ(q) ADECL1(0, q) ADECL1(1, q) ADECL1(2, q) ADECL1(3, q)

#define AW(dst, src) asm volatile("v_accvgpr_write_b32 %0, %1" : "=a"(dst) : "v"(src));
#define AINIT(c, q) { const uint4 t_ = wqa[((q) * 4 + (c)) * 64]; \
    AW(A##c##_##q##_0, t_.x) AW(A##c##_##q##_1, t_.y) \
    AW(A##c##_##q##_2, t_.z) AW(A##c##_##q##_3, t_.w) }
#define AINITQ(q) AINIT(0, q) AINIT(1, q) AINIT(2, q) AINIT(3, q)

#define AR(dst, src) asm volatile("v_accvgpr_read_b32 %0, %1" : "=v"(dst) : "a"(src));

#define AGDOT(c, q, HQ) { u32 t0_, t1_, t2_, t3_; \
    AR(t0_, A##c##_##q##_0) AR(t1_, A##c##_##q##_1) \
    AR(t2_, A##c##_##q##_2) AR(t3_, A##c##_##q##_3) \
    acc##c = fdot2(BCH((HQ).x), BCH(t0_), acc##c); \
    acc##c = fdot2(BCH((HQ).y), BCH(t1_), acc##c); \
    acc##c = fdot2(BCH((HQ).z), BCH(t2_), acc##c); \
    acc##c = fdot2(BCH((HQ).w), BCH(t3_), acc##c); }

#define DOTQ(HQ, WQ, ACC) \
    ACC = fdot2(BCH((HQ).x), BCH((WQ).x), ACC); \
    ACC = fdot2(BCH((HQ).y), BCH((WQ).y), ACC); \
    ACC = fdot2(BCH((HQ).z), BCH((WQ).z), ACC); \
    ACC = fdot2(BCH((HQ).w), BCH((WQ).w), ACC);

#define REFILL(P0, P1, P2, P3) \
    P0 = wcur[0]; P1 = wcur[64]; P2 = wcur[128]; P3 = wcur[192]; wcur += 256;

#define GRP(q, HQ, P0, P1, P2, P3) \
    AGDOT(0, q, HQ) AGDOT(1, q, HQ) AGDOT(2, q, HQ) AGDOT(3, q, HQ) \
    DOTQ(HQ, P0, acc4) DOTQ(HQ, P1, acc5) DOTQ(HQ, P2, acc6) DOTQ(HQ, P3, acc7)

__global__ __launch_bounds__(512)
void rnn_seq(const float* __restrict__ h0,    // [NB][NH]
             const u16* __restrict__ U,       // [NB*NT][NH] f16
             u16* __restrict__ H,             // [NB*NT][NH] f16 (out)
             const uint4* __restrict__ Wpk) { // packed W_hh f16, 32768 uint4
    const int b = blockIdx.x;
    const int tid = threadIdx.x;
    const int w = tid >> 6, l = tid & 63;

    __shared__ __align__(16) float part2[8][8][72];  // partials, 18 KiB, conflict-free
    __shared__ __align__(16) u32 h2u[NH / 2];        // h as f16 pairs, 1 KiB

    // AGPR bank: cols 8l+0..3 over k in [64w, 64w+64), 128 a-regs (one-time coalesced init).
    ADECLQ(0) ADECLQ(1) ADECLQ(2) ADECLQ(3) ADECLQ(4) ADECLQ(5) ADECLQ(6) ADECLQ(7)
    const uint4* __restrict__ wqa = Wpk + (size_t)w * 2048 + l;
    AINITQ(0) AINITQ(1) AINITQ(2) AINITQ(3) AINITQ(4) AINITQ(5) AINITQ(6) AINITQ(7)

    float hreg = h0[b * NH + tid];
    if (tid < NH / 2) {
        float2 hv = *reinterpret_cast<const float2*>(&h0[b * NH + 2 * tid]);
        half2_t hp; hp[0] = (_Float16)hv.x; hp[1] = (_Float16)hv.y;
        h2u[tid] = __builtin_bit_cast(u32, hp);
    }
    __syncthreads();

    const u16* __restrict__ Urow = U + (size_t)b * NT * NH + tid;
    u16* __restrict__ Hrow = H + (size_t)b * NT * NH + tid;
    const uint4* __restrict__ wqs0 = Wpk + 16384 + (size_t)w * 2048 + l;  // stream base (g0)
    const uint4* __restrict__ hqb = reinterpret_cast<const uint4*>(h2u) + (w << 3);

    // Stream double-buffer: 8 named quads, primed with groups g0 (pa) and g1 (pb).
    const uint4* wcur = wqs0;
    uint4 pa0, pa1, pa2, pa3, pb0, pb1, pb2, pb3;
    REFILL(pa0, pa1, pa2, pa3)   // g0; wcur -> g1
    REFILL(pb0, pb1, pb2, pb3)   // g1; wcur -> g2 (steady state)

    u16 ub_cur = Urow[0];

    #pragma unroll 1
    for (int t = 0; t < NT; ++t) {
        const u16 ub_nxt = Urow[(size_t)(t + 1) * NH];   // one step ahead (safe: H follows U)

        uint4 hqA = hqb[0], hqB = hqb[1];
        float acc0 = 0.f, acc1 = 0.f, acc2 = 0.f, acc3 = 0.f;
        float acc4 = 0.f, acc5 = 0.f, acc6 = 0.f, acc7 = 0.f;

        GRP(0, hqA, pa0, pa1, pa2, pa3) hqA = hqb[2]; REFILL(pa0, pa1, pa2, pa3)   // g2
        GRP(1, hqB, pb0, pb1, pb2, pb3) hqB = hqb[3]; REFILL(pb0, pb1, pb2, pb3)   // g3
        GRP(2, hqA, pa0, pa1, pa2, pa3) hqA = hqb[4]; REFILL(pa0, pa1, pa2, pa3)   // g4
        GRP(3, hqB, pb0, pb1, pb2, pb3) hqB = hqb[5]; REFILL(pb0, pb1, pb2, pb3)   // g5
        GRP(4, hqA, pa0, pa1, pa2, pa3) hqA = hqb[6]; REFILL(pa0, pa1, pa2, pa3)   // g6
        GRP(5, hqB, pb0, pb1, pb2, pb3) hqB = hqb[7]; REFILL(pb0, pb1, pb2, pb3)   // g7
        wcur = wqs0;                                                                // rewind
        GRP(6, hqA, pa0, pa1, pa2, pa3) REFILL(pa0, pa1, pa2, pa3)   // g0 (next step)
        GRP(7, hqB, pb0, pb1, pb2, pb3) REFILL(pb0, pb1, pb2, pb3)   // g1 (next step)

        // Partials: col 8l+i -> part2[w][i][l]; lanes consecutive => conflict-free.
        part2[w][0][l] = acc0; part2[w][1][l] = acc1;
        part2[w][2][l] = acc2; part2[w][3][l] = acc3;
        part2[w][4][l] = acc4; part2[w][5][l] = acc5;
        part2[w][6][l] = acc6; part2[w][7][l] = acc7;
        __syncthreads();

        // Update h[tid]: 8-way k-chunk reduction; 72%32=8 => 8i+l distinct => free.
        const int ii = tid & 7, lr = tid >> 3;
        const float pre = (((part2[0][ii][lr] + part2[1][ii][lr])
                          + (part2[2][ii][lr] + part2[3][ii][lr]))
                         + ((part2[4][ii][lr] + part2[5][ii][lr])
                          + (part2[6][ii][lr] + part2[7][ii][lr])))
                        + htof(ub_cur);
        const float e = __expf(2.f * pre);
        hreg = 0.9f * hreg + 0.1f * (1.f - 2.f / (e + 1.f));
        const u16 hb = ftoh(hreg);
        Hrow[(size_t)t * NH] = hb;
        reinterpret_cast<u16*>(h2u)[tid] = hb;
        ub_cur = ub_nxt;
        __syncthreads();
    }
}

// ---------------- Phase 3: Y[m][n] = H[m][:] @ W_hy[:,n] + b_y[n]  (fp32 out) ----------------
__global__ __launch_bounds__(256) void y_gemm(
        const u16* __restrict__ H,      // [M][NH] f16
        const float* __restrict__ Why,  // [NH][NO]
        const float* __restrict__ by,   // [NO]
        float* __restrict__ Y) {        // [M][NO]
    const int m0 = blockIdx.x * 64;
    const int tid = threadIdx.x;
    const int tn = tid & 15, tm = tid >> 4;
    __shared__ float As[64][68];    // [k][m]
    __shared__ float Bs[64][132];   // [k][n]
    float acc[4][8] = {};
    for (int k0 = 0; k0 < NH; k0 += 64) {
        #pragma unroll
        for (int p = 0; p < 4; ++p) {
            const int idx = tid + p * 256;
            const int r = idx >> 4;
            const int c4 = idx & 15;
            ushort4 v = *reinterpret_cast<const ushort4*>(&H[(size_t)(m0 + r) * NH + k0 + c4 * 4]);
            As[c4 * 4 + 0][r] = htof(v.x); As[c4 * 4 + 1][r] = htof(v.y);
            As[c4 * 4 + 2][r] = htof(v.z); As[c4 * 4 + 3][r] = htof(v.w);
        }
        #pragma unroll
        for (int p = 0; p < 8; ++p) {
            const int idx = tid + p * 256;
            const int r = idx >> 5;
            const int c4 = idx & 31;
            float4 v = *reinterpret_cast<const float4*>(&Why[(size_t)(k0 + r) * NO + c4 * 4]);
            *reinterpret_cast<float4*>(&Bs[r][c4 * 4]) = v;
        }
        __syncthreads();
        #pragma unroll
        for (int kk = 0; kk < 64; ++kk) {
            float4 av = *reinterpret_cast<const float4*>(&As[kk][tm * 4]);
            float4 b0 = *reinterpret_cast<const float4*>(&Bs[kk][tn * 8]);
            float4 b1 = *reinterpret_cast<const float4*>(&Bs[kk][tn * 8 + 4]);
            const float am[4] = {av.x, av.y, av.z, av.w};
            const float bn[8] = {b0.x, b0.y, b0.z, b0.w, b1.x, b1.y, b1.z, b1.w};
            #pragma unroll
            for (int i = 0; i < 4; ++i)
                #pragma unroll
                for (int j = 0; j < 8; ++j)
                    acc[i][j] += am[i] * bn[j];
        }
        __syncthreads();
    }
    float bias[8];
    #pragma unroll
    for (int j = 0; j < 8; ++j) bias[j] = by[tn * 8 + j];
    #pragma unroll
    for (int i = 0; i < 4; ++i) {
        const int m = m0 + tm * 4 + i;
        float4 o0, o1;
        o0.x = acc[i][0] + bias[0]; o0.y = acc[i][1] + bias[1];
        o0.z = acc[i][2] + bias[2]; o0.w = acc[i][3] + bias[3];
        o1.x = acc[i][4] + bias[4]; o1.y = acc[i][5] + bias[5];
        o1.z = acc[i][6] + bias[6]; o1.w = acc[i][7] + bias[7];
        *reinterpret_cast<float4*>(&Y[(size_t)m * NO + tn * 8]) = o0;
        *reinterpret_cast<float4*>(&Y[(size_t)m * NO + tn * 8 + 4]) = o1;
    }
}

extern "C" void kernel_launch(void* const* d_in, const int* in_sizes, int n_in,
                              void* d_out, int out_size, void* d_ws, size_t ws_size,
                              hipStream_t stream) {
    const float* u   = (const float*)d_in[0];   // [64][2048][128]
    const float* h0  = (const float*)d_in[1];   // [64][512]
    const float* Wuh = (const float*)d_in[2];   // [128][512]
    const float* Whh = (const float*)d_in[3];   // [512][512]
    const float* Why = (const float*)d_in[4];   // [512][128]
    const float* bh  = (const float*)d_in[5];   // [512]
    const float* by  = (const float*)d_in[6];   // [128]
    float* y = (float*)d_out;                   // [64][2048][128] fp32

    u16* Uws = (u16*)d_ws;                       // 128 MiB
    u16* Hws = Uws + (size_t)NB * NT * NH;       // 128 MiB
    uint4* Wpk = (uint4*)d_out;                  // 512 KiB, dead until y_gemm
    (void)in_sizes; (void)n_in; (void)out_size; (void)ws_size;

    wpack<<<dim3(128), 256, 0, stream>>>(Whh, Wpk);
    u_gemm<<<dim3(NH / 64, (NB * NT) / 64), 256, 0, stream>>>(u, Wuh, bh, Uws);
    rnn_seq<<<dim3(NB), 512, 0, stream>>>(h0, Uws, Hws, Wpk);
    y_gemm<<<dim3((NB * NT) / 64), 256, 0, stream>>>(Hws, Why, by, y);
}

// Round 10
// 2511.103 us; speedup vs baseline: 2.0585x; 2.0585x over previous
//
#include <hip/hip_runtime.h>
#include <cmath>

// Leaky RNN:  h_t = 0.9 h_{t-1} + 0.1 tanh(h W_hh + u_t W_uh + b_h);  y_t = h_t W_hy + b_y
// B=64, T=2048, N_in=128, N_h=512, N_out=128.
//
// Phase 2 (critical path): one WG per batch row, 512 threads = 8 waves.  Round-9 accounting:
// the f16 design streams 393 KB/CU/step -> per-CU L2-load-bandwidth bound (~3600cy).  Fix:
// W_hh quantized to INT8 with per-column scales; matvec via v_dot4_i32_i8 with exact int32
// accumulation.  W int8 = 256 KB: 128 KB LDS-resident (cols 8l+0..3) + 128 KB streamed
// (cols 8l+4..7, 256 B/thread/step).  h quantized to int8 (fixed scale S_H, clamped) into a
// 512-B LDS buffer each step; the f32 recurrence state stays full precision, so quant error
// only enters through the alpha=0.1-damped pre path.  pre[n] = isum * c_n + U, c_n = S_H *
// colmax_n / 127^2.  Partials int32 in part2[8][8][72].  2 barriers/step.
//
// ws: U (f16 [B*T][512], 128 MiB) | H (f16 [B*T][512], 128 MiB).
// Wpk (256 KiB int8 W) + scale bufs live in d_out (dead until y_gemm runs last).

#define NB 64
#define NT 2048
#define NI 128
#define NH 512
#define NO 128
#define S_H 4.6f

typedef unsigned short u16;
typedef unsigned int u32;
typedef _Float16 half2_t __attribute__((ext_vector_type(2)));

__device__ __forceinline__ int sdot4(u32 a, u32 b, int c) {
#if __has_builtin(__builtin_amdgcn_sdot4)
    return __builtin_amdgcn_sdot4(a, b, c, false);
#else
    int r = c;
    r += (int)(signed char)(a) * (int)(signed char)(b);
    r += (int)(signed char)(a >> 8) * (int)(signed char)(b >> 8);
    r += (int)(signed char)(a >> 16) * (int)(signed char)(b >> 16);
    r += (int)(signed char)(a >> 24) * (int)(signed char)(b >> 24);
    return r;
#endif
}

__device__ __forceinline__ u16 ftoh(float x) { return __builtin_bit_cast(u16, (_Float16)x); }
__device__ __forceinline__ float htof(u16 x) { return (float)__builtin_bit_cast(_Float16, x); }

// ---------------- Phase -1: per-column |max| of W_hh -> scales ----------------
// sbuf[n] = colmax/127 (quant step), cbuf[n] = S_H*colmax/127^2 (pre-scale).
__global__ __launch_bounds__(256) void wscale(const float* __restrict__ Whh,
                                              float* __restrict__ sbuf,
                                              float* __restrict__ cbuf) {
    const int n0 = blockIdx.x * 64;
    const int r = threadIdx.x >> 6, c = threadIdx.x & 63;
    const int n = n0 + c;
    float m = 0.f;
    for (int k = r; k < NH; k += 4) m = fmaxf(m, fabsf(Whh[(size_t)k * NH + n]));
    __shared__ float red[4][64];
    red[r][c] = m;
    __syncthreads();
    if (r == 0) {
        m = fmaxf(fmaxf(red[0][c], red[1][c]), fmaxf(red[2][c], red[3][c]));
        m = fmaxf(m, 1e-8f);
        sbuf[n] = m * (1.f / 127.f);
        cbuf[n] = S_H * m * (1.f / 16129.f);
    }
}

// ---------------- Phase 0: pack W_hh to int8, consumer order ----------------
// idx: sec=idx>>13 (0:LDS cols 8l+0..3, 1:stream cols 8l+4..7); r13=idx&8191:
// l=r13&63, c=(r13>>6)&3, g=(r13>>8)&3, w=r13>>10.  col=8l+4*sec+c, kb=64w+16g,
// uint4 = 16 int8 for k=kb..kb+15 (word j = k-quad kb+4j..+3).
__global__ __launch_bounds__(256) void wpack(const float* __restrict__ Whh,
                                             const float* __restrict__ sbuf,
                                             uint4* __restrict__ Wpk) {
    const int idx = blockIdx.x * 256 + threadIdx.x;   // 0..16383
    const int sec = idx >> 13;
    const int r13 = idx & 8191;
    const int l = r13 & 63, c = (r13 >> 6) & 3, g = (r13 >> 8) & 3, w = r13 >> 10;
    const int col = 8 * l + 4 * sec + c;
    const int kb = 64 * w + 16 * g;
    const float inv = 1.f / sbuf[col];
    u32 words[4];
    #pragma unroll
    for (int wd = 0; wd < 4; ++wd) {
        u32 acc = 0;
        #pragma unroll
        for (int j = 0; j < 4; ++j) {
            const int k = kb + wd * 4 + j;
            float q = rintf(Whh[(size_t)k * NH + col] * inv);
            q = fminf(fmaxf(q, -127.f), 127.f);
            acc |= ((u32)((int)q & 0xFF)) << (8 * j);
        }
        words[wd] = acc;
    }
    uint4 o; o.x = words[0]; o.y = words[1]; o.z = words[2]; o.w = words[3];
    Wpk[idx] = o;
}

// ---------------- Phase 1: U[m][n] = u[m][:] @ W_uh[:,n] + b_h[n]  (f16 out) ----------------
__global__ __launch_bounds__(256) void u_gemm(
        const float* __restrict__ A,    // u  [M][NI]
        const float* __restrict__ Bw,   // W_uh [NI][NH]
        const float* __restrict__ bh,   // [NH]
        u16* __restrict__ C) {          // U [M][NH] f16
    const int n0 = blockIdx.x * 64;
    const int m0 = blockIdx.y * 64;
    const int tid = threadIdx.x;
    const int tn = tid & 15, tm = tid >> 4;
    __shared__ float As[64][68];   // [k][m]
    __shared__ float Bs[64][68];   // [k][n]
    float acc[4][4] = {};
    for (int k0 = 0; k0 < NI; k0 += 64) {
        const int r = tid >> 4, c4 = tid & 15;
        #pragma unroll
        for (int p = 0; p < 4; ++p) {
            const int row = r + p * 16;
            float4 v = *reinterpret_cast<const float4*>(&A[(size_t)(m0 + row) * NI + k0 + c4 * 4]);
            As[c4 * 4 + 0][row] = v.x; As[c4 * 4 + 1][row] = v.y;
            As[c4 * 4 + 2][row] = v.z; As[c4 * 4 + 3][row] = v.w;
        }
        #pragma unroll
        for (int p = 0; p < 4; ++p) {
            const int row = r + p * 16;
            float4 v = *reinterpret_cast<const float4*>(&Bw[(size_t)(k0 + row) * NH + n0 + c4 * 4]);
            *reinterpret_cast<float4*>(&Bs[row][c4 * 4]) = v;
        }
        __syncthreads();
        #pragma unroll
        for (int kk = 0; kk < 64; ++kk) {
            float4 av = *reinterpret_cast<const float4*>(&As[kk][tm * 4]);
            float4 bv = *reinterpret_cast<const float4*>(&Bs[kk][tn * 4]);
            const float am[4] = {av.x, av.y, av.z, av.w};
            const float bn[4] = {bv.x, bv.y, bv.z, bv.w};
            #pragma unroll
            for (int i = 0; i < 4; ++i)
                #pragma unroll
                for (int j = 0; j < 4; ++j)
                    acc[i][j] += am[i] * bn[j];
        }
        __syncthreads();
    }
    float bias[4];
    #pragma unroll
    for (int j = 0; j < 4; ++j) bias[j] = bh[n0 + tn * 4 + j];
    #pragma unroll
    for (int i = 0; i < 4; ++i) {
        const int m = m0 + tm * 4 + i;
        ushort4 out;
        out.x = ftoh(acc[i][0] + bias[0]);
        out.y = ftoh(acc[i][1] + bias[1]);
        out.z = ftoh(acc[i][2] + bias[2]);
        out.w = ftoh(acc[i][3] + bias[3]);
        *reinterpret_cast<ushort4*>(&C[(size_t)m * NH + n0 + tn * 4]) = out;
    }
}

// ---------------- Phase 2: sequential recurrence (int8 dot4) ----------------
// 16 int8 k's of one column vs h: 4 sdot4.
#define DOT16(HG, WQ, ACC)                 \
    ACC = sdot4((HG).x, (WQ).x, ACC);      \
    ACC = sdot4((HG).y, (WQ).y, ACC);      \
    ACC = sdot4((HG).z, (WQ).z, ACC);      \
    ACC = sdot4((HG).w, (WQ).w, ACC);

#define GRPDOT(HG, D0, D1, D2, D3, S0, S1, S2, S3)             \
    DOT16(HG, D0, acc0) DOT16(HG, D1, acc1)                    \
    DOT16(HG, D2, acc2) DOT16(HG, D3, acc3)                    \
    DOT16(HG, S0, acc4) DOT16(HG, S1, acc5)                    \
    DOT16(HG, S2, acc6) DOT16(HG, S3, acc7)

#define LDSPF(D0, D1, D2, D3, g)           \
    D0 = wls[((g) * 4 + 0) * 64];          \
    D1 = wls[((g) * 4 + 1) * 64];          \
    D2 = wls[((g) * 4 + 2) * 64];          \
    D3 = wls[((g) * 4 + 3) * 64];

#define SREF(S0, S1, S2, S3, WB)           \
    S0 = (WB)[0];   S1 = (WB)[64];         \
    S2 = (WB)[128]; S3 = (WB)[192];

__global__ __launch_bounds__(512)
void rnn_seq(const float* __restrict__ h0,    // [NB][NH]
             const u16* __restrict__ U,       // [NB*NT][NH] f16
             u16* __restrict__ H,             // [NB*NT][NH] f16 (out)
             const uint4* __restrict__ Wpk,   // int8 W, 16384 uint4 (L:8192, S:8192)
             const float* __restrict__ cbuf) {// per-col pre-scales [NH]
    const int b = blockIdx.x;
    const int tid = threadIdx.x;
    const int w = tid >> 6, l = tid & 63;

    __shared__ __align__(16) uint4 Wl[8192];        // LDS-resident int8 W, 128 KiB
    __shared__ __align__(16) int part2[8][8][72];   // int32 partials, 18 KiB
    __shared__ __align__(16) u32 h8[NH / 4];        // int8 h, 512 B
    __shared__ float cf[NH];                        // pre-scales, 2 KiB

    // One-time: copy LDS W section (coalesced b128) + scales; quantize h0.
    #pragma unroll
    for (int j = 0; j < 16; ++j) Wl[j * 512 + tid] = Wpk[j * 512 + tid];
    cf[tid] = cbuf[tid];
    float hreg = h0[b * NH + tid];
    {
        float q = rintf(hreg * (127.f / S_H));
        q = fminf(fmaxf(q, -127.f), 127.f);
        reinterpret_cast<unsigned char*>(h8)[tid] = (unsigned char)((int)q);
    }
    __syncthreads();

    const u16* __restrict__ Urow = U + (size_t)b * NT * NH + tid;
    u16* __restrict__ Hrow = H + (size_t)b * NT * NH + tid;
    const uint4* __restrict__ wls = Wl + w * 1024 + l;                  // LDS W base
    const uint4* __restrict__ wqs = Wpk + 8192 + (size_t)w * 1024 + l;  // stream base
    const uint4* __restrict__ wq0 = wqs;                                // group bases
    const uint4* __restrict__ wq1 = wqs + 256;
    const uint4* __restrict__ wq2 = wqs + 512;
    const uint4* __restrict__ wq3 = wqs + 768;
    const uint4* __restrict__ hq4v = reinterpret_cast<const uint4*>(h8) + (w << 2);

    // Primed state (step-invariant W): LDS g0 + stream g0/g1.
    uint4 dA0, dA1, dA2, dA3, dB0, dB1, dB2, dB3;
    uint4 sA0, sA1, sA2, sA3, sB0, sB1, sB2, sB3;
    LDSPF(dA0, dA1, dA2, dA3, 0)
    SREF(sA0, sA1, sA2, sA3, wq0)
    SREF(sB0, sB1, sB2, sB3, wq1)

    u16 ub_cur = Urow[0];

    #pragma unroll 1
    for (int t = 0; t < NT; ++t) {
        const u16 ub_nxt = Urow[(size_t)(t + 1) * NH];   // one step ahead (H follows U)

        uint4 hA = hq4v[0], hB = hq4v[1];
        int acc0 = 0, acc1 = 0, acc2 = 0, acc3 = 0;
        int acc4 = 0, acc5 = 0, acc6 = 0, acc7 = 0;

        // G0 (k 64w+0..15)
        LDSPF(dB0, dB1, dB2, dB3, 1)
        GRPDOT(hA, dA0, dA1, dA2, dA3, sA0, sA1, sA2, sA3)
        hA = hq4v[2];
        SREF(sA0, sA1, sA2, sA3, wq2)
        // G1
        LDSPF(dA0, dA1, dA2, dA3, 2)
        GRPDOT(hB, dB0, dB1, dB2, dB3, sB0, sB1, sB2, sB3)
        hB = hq4v[3];
        SREF(sB0, sB1, sB2, sB3, wq3)
        // G2
        LDSPF(dB0, dB1, dB2, dB3, 3)
        GRPDOT(hA, dA0, dA1, dA2, dA3, sA0, sA1, sA2, sA3)
        SREF(sA0, sA1, sA2, sA3, wq0)   // next step g0
        // G3
        LDSPF(dA0, dA1, dA2, dA3, 0)    // next step g0 (LDS W invariant)
        GRPDOT(hB, dB0, dB1, dB2, dB3, sB0, sB1, sB2, sB3)
        SREF(sB0, sB1, sB2, sB3, wq1)   // next step g1

        // Partials: col 8l+i -> part2[w][i][l]; lanes consecutive => conflict-free.
        part2[w][0][l] = acc0; part2[w][1][l] = acc1;
        part2[w][2][l] = acc2; part2[w][3][l] = acc3;
        part2[w][4][l] = acc4; part2[w][5][l] = acc5;
        part2[w][6][l] = acc6; part2[w][7][l] = acc7;
        __syncthreads();

        // Update h[tid] (col tid = 8*(tid>>3) + (tid&7)): exact int32 k-reduction.
        const int ii = tid & 7, lr = tid >> 3;
        const int isum = ((part2[0][ii][lr] + part2[1][ii][lr])
                        + (part2[2][ii][lr] + part2[3][ii][lr]))
                       + ((part2[4][ii][lr] + part2[5][ii][lr])
                        + (part2[6][ii][lr] + part2[7][ii][lr]));
        const float pre = (float)isum * cf[tid] + htof(ub_cur);
        const float e = __expf(2.f * pre);
        hreg = 0.9f * hreg + 0.1f * (1.f - 2.f / (e + 1.f));
        Hrow[(size_t)t * NH] = ftoh(hreg);
        float q = rintf(hreg * (127.f / S_H));
        q = fminf(fmaxf(q, -127.f), 127.f);
        reinterpret_cast<unsigned char*>(h8)[tid] = (unsigned char)((int)q);
        ub_cur = ub_nxt;
        __syncthreads();
    }
}

// ---------------- Phase 3: Y[m][n] = H[m][:] @ W_hy[:,n] + b_y[n]  (fp32 out) ----------------
__global__ __launch_bounds__(256) void y_gemm(
        const u16* __restrict__ H,      // [M][NH] f16
        const float* __restrict__ Why,  // [NH][NO]
        const float* __restrict__ by,   // [NO]
        float* __restrict__ Y) {        // [M][NO]
    const int m0 = blockIdx.x * 64;
    const int tid = threadIdx.x;
    const int tn = tid & 15, tm = tid >> 4;
    __shared__ float As[64][68];    // [k][m]
    __shared__ float Bs[64][132];   // [k][n]
    float acc[4][8] = {};
    for (int k0 = 0; k0 < NH; k0 += 64) {
        #pragma unroll
        for (int p = 0; p < 4; ++p) {
            const int idx = tid + p * 256;
            const int r = idx >> 4;
            const int c4 = idx & 15;
            ushort4 v = *reinterpret_cast<const ushort4*>(&H[(size_t)(m0 + r) * NH + k0 + c4 * 4]);
            As[c4 * 4 + 0][r] = htof(v.x); As[c4 * 4 + 1][r] = htof(v.y);
            As[c4 * 4 + 2][r] = htof(v.z); As[c4 * 4 + 3][r] = htof(v.w);
        }
        #pragma unroll
        for (int p = 0; p < 8; ++p) {
            const int idx = tid + p * 256;
            const int r = idx >> 5;
            const int c4 = idx & 31;
            float4 v = *reinterpret_cast<const float4*>(&Why[(size_t)(k0 + r) * NO + c4 * 4]);
            *reinterpret_cast<float4*>(&Bs[r][c4 * 4]) = v;
        }
        __syncthreads();
        #pragma unroll
        for (int kk = 0; kk < 64; ++kk) {
            float4 av = *reinterpret_cast<const float4*>(&As[kk][tm * 4]);
            float4 b0 = *reinterpret_cast<const float4*>(&Bs[kk][tn * 8]);
            float4 b1 = *reinterpret_cast<const float4*>(&Bs[kk][tn * 8 + 4]);
            const float am[4] = {av.x, av.y, av.z, av.w};
            const float bn[8] = {b0.x, b0.y, b0.z, b0.w, b1.x, b1.y, b1.z, b1.w};
            #pragma unroll
            for (int i = 0; i < 4; ++i)
                #pragma unroll
                for (int j = 0; j < 8; ++j)
                    acc[i][j] += am[i] * bn[j];
        }
        __syncthreads();
    }
    float bias[8];
    #pragma unroll
    for (int j = 0; j < 8; ++j) bias[j] = by[tn * 8 + j];
    #pragma unroll
    for (int i = 0; i < 4; ++i) {
        const int m = m0 + tm * 4 + i;
        float4 o0, o1;
        o0.x = acc[i][0] + bias[0]; o0.y = acc[i][1] + bias[1];
        o0.z = acc[i][2] + bias[2]; o0.w = acc[i][3] + bias[3];
        o1.x = acc[i][4] + bias[4]; o1.y = acc[i][5] + bias[5];
        o1.z = acc[i][6] + bias[6]; o1.w = acc[i][7] + bias[7];
        *reinterpret_cast<float4*>(&Y[(size_t)m * NO + tn * 8]) = o0;
        *reinterpret_cast<float4*>(&Y[(size_t)m * NO + tn * 8 + 4]) = o1;
    }
}

extern "C" void kernel_launch(void* const* d_in, const int* in_sizes, int n_in,
                              void* d_out, int out_size, void* d_ws, size_t ws_size,
                              hipStream_t stream) {
    const float* u   = (const float*)d_in[0];   // [64][2048][128]
    const float* h0  = (const float*)d_in[1];   // [64][512]
    const float* Wuh = (const float*)d_in[2];   // [128][512]
    const float* Whh = (const float*)d_in[3];   // [512][512]
    const float* Why = (const float*)d_in[4];   // [512][128]
    const float* bh  = (const float*)d_in[5];   // [512]
    const float* by  = (const float*)d_in[6];   // [128]
    float* y = (float*)d_out;                   // [64][2048][128] fp32

    u16* Uws = (u16*)d_ws;                       // 128 MiB
    u16* Hws = Uws + (size_t)NB * NT * NH;       // 128 MiB
    // Scratch in d_out (dead until y_gemm overwrites all of it last):
    uint4* Wpk  = (uint4*)d_out;                 // 256 KiB int8 W
    float* sbuf = (float*)(Wpk + 16384);         // 2 KiB quant steps
    float* cbuf = sbuf + NH;                     // 2 KiB pre-scales
    (void)in_sizes; (void)n_in; (void)out_size; (void)ws_size;

    wscale<<<dim3(8), 256, 0, stream>>>(Whh, sbuf, cbuf);
    wpack<<<dim3(64), 256, 0, stream>>>(Whh, sbuf, Wpk);
    u_gemm<<<dim3(NH / 64, (NB * NT) / 64), 256, 0, stream>>>(u, Wuh, bh, Uws);
    rnn_seq<<<dim3(NB), 512, 0, stream>>>(h0, Uws, Hws, Wpk, cbuf);
    y_gemm<<<dim3((NB * NT) / 64), 256, 0, stream>>>(Hws, Why, by, y);
}

// Round 11
// 2275.262 us; speedup vs baseline: 2.2718x; 1.1037x over previous
//
#include <hip/hip_runtime.h>
#include <cmath>

// Leaky RNN:  h_t = 0.9 h_{t-1} + 0.1 tanh(h W_hh + u_t W_uh + b_h);  y_t = h_t W_hy + b_y
// B=64, T=2048, N_in=128, N_h=512, N_out=128.
//
// Phase 2 (critical path): one WG per batch row, now 1024 threads = 16 waves (4/SIMD) —
// round-10's pipes (L2 ~1160cy, LDS ~1300cy, VALU ~1100cy per step) weren't overlapping at
// 2 waves/SIMD; int8's low VGPR demand (~65) makes 4 waves/SIMD feasible.  Wave (kc=w&7,
// ch=w>>3): k-chunk [64kc,64kc+64) x column-half ch.  Lane l: cols ch*256+4l+{0,1} from
// LDS-resident int8 W (128 KiB), cols +{2,3} streamed from L2 (128 KB/step/CU).  Exact
// int32 accumulation via v_dot4_i32_i8; per-column scales; h int8 (fixed S_H) in 512-B LDS;
// f32 recurrence state.  Partials int32 [8][512] (int4 writes / strided reads, both
// conflict-free).  2 barriers/step.
//
// ws: U (f16 [B*T][512], 128 MiB) | H (f16 [B*T][512], 128 MiB).
// Wpk (256 KiB int8 W) + scale bufs live in d_out (dead until y_gemm runs last).

#define NB 64
#define NT 2048
#define NI 128
#define NH 512
#define NO 128
#define S_H 4.6f

typedef unsigned short u16;
typedef unsigned int u32;
typedef _Float16 half2_t __attribute__((ext_vector_type(2)));

__device__ __forceinline__ int sdot4(u32 a, u32 b, int c) {
#if __has_builtin(__builtin_amdgcn_sdot4)
    return __builtin_amdgcn_sdot4(a, b, c, false);
#else
    int r = c;
    r += (int)(signed char)(a) * (int)(signed char)(b);
    r += (int)(signed char)(a >> 8) * (int)(signed char)(b >> 8);
    r += (int)(signed char)(a >> 16) * (int)(signed char)(b >> 16);
    r += (int)(signed char)(a >> 24) * (int)(signed char)(b >> 24);
    return r;
#endif
}

__device__ __forceinline__ u16 ftoh(float x) { return __builtin_bit_cast(u16, (_Float16)x); }
__device__ __forceinline__ float htof(u16 x) { return (float)__builtin_bit_cast(_Float16, x); }

// ---------------- Phase -1: per-column |max| of W_hh -> scales ----------------
__global__ __launch_bounds__(256) void wscale(const float* __restrict__ Whh,
                                              float* __restrict__ sbuf,
                                              float* __restrict__ cbuf) {
    const int n0 = blockIdx.x * 64;
    const int r = threadIdx.x >> 6, c = threadIdx.x & 63;
    const int n = n0 + c;
    float m = 0.f;
    for (int k = r; k < NH; k += 4) m = fmaxf(m, fabsf(Whh[(size_t)k * NH + n]));
    __shared__ float red[4][64];
    red[r][c] = m;
    __syncthreads();
    if (r == 0) {
        m = fmaxf(fmaxf(red[0][c], red[1][c]), fmaxf(red[2][c], red[3][c]));
        m = fmaxf(m, 1e-8f);
        sbuf[n] = m * (1.f / 127.f);
        cbuf[n] = S_H * m * (1.f / 16129.f);
    }
}

// ---------------- Phase 0: pack W_hh to int8, consumer order ----------------
// idx = sec*8192 + ((((ch*8+kc)*4+q)*2+ci)*64 + l.  sec 0: LDS cols ch*256+4l+ci;
// sec 1: stream cols ch*256+4l+2+ci.  kb = kc*64 + q*16; uint4 = 16 int8, word j =
// k = kb+4j..+3.
__global__ __launch_bounds__(256) void wpack(const float* __restrict__ Whh,
                                             const float* __restrict__ sbuf,
                                             uint4* __restrict__ Wpk) {
    const int idx = blockIdx.x * 256 + threadIdx.x;   // 0..16383
    const int sec = idx >> 13;
    const int r = idx & 8191;
    const int l = r & 63;
    const int ci = (r >> 6) & 1;
    const int q = (r >> 7) & 3;
    const int kc = (r >> 9) & 7;
    const int ch = r >> 12;
    const int col = ch * 256 + 4 * l + (sec ? 2 : 0) + ci;
    const int kb = kc * 64 + q * 16;
    const float inv = 1.f / sbuf[col];
    u32 words[4];
    #pragma unroll
    for (int wd = 0; wd < 4; ++wd) {
        u32 acc = 0;
        #pragma unroll
        for (int j = 0; j < 4; ++j) {
            const int k = kb + wd * 4 + j;
            float qv = rintf(Whh[(size_t)k * NH + col] * inv);
            qv = fminf(fmaxf(qv, -127.f), 127.f);
            acc |= ((u32)((int)qv & 0xFF)) << (8 * j);
        }
        words[wd] = acc;
    }
    uint4 o; o.x = words[0]; o.y = words[1]; o.z = words[2]; o.w = words[3];
    Wpk[idx] = o;
}

// ---------------- Phase 1: U[m][n] = u[m][:] @ W_uh[:,n] + b_h[n]  (f16 out) ----------------
__global__ __launch_bounds__(256) void u_gemm(
        const float* __restrict__ A,    // u  [M][NI]
        const float* __restrict__ Bw,   // W_uh [NI][NH]
        const float* __restrict__ bh,   // [NH]
        u16* __restrict__ C) {          // U [M][NH] f16
    const int n0 = blockIdx.x * 64;
    const int m0 = blockIdx.y * 64;
    const int tid = threadIdx.x;
    const int tn = tid & 15, tm = tid >> 4;
    __shared__ float As[64][68];   // [k][m]
    __shared__ float Bs[64][68];   // [k][n]
    float acc[4][4] = {};
    for (int k0 = 0; k0 < NI; k0 += 64) {
        const int r = tid >> 4, c4 = tid & 15;
        #pragma unroll
        for (int p = 0; p < 4; ++p) {
            const int row = r + p * 16;
            float4 v = *reinterpret_cast<const float4*>(&A[(size_t)(m0 + row) * NI + k0 + c4 * 4]);
            As[c4 * 4 + 0][row] = v.x; As[c4 * 4 + 1][row] = v.y;
            As[c4 * 4 + 2][row] = v.z; As[c4 * 4 + 3][row] = v.w;
        }
        #pragma unroll
        for (int p = 0; p < 4; ++p) {
            const int row = r + p * 16;
            float4 v = *reinterpret_cast<const float4*>(&Bw[(size_t)(k0 + row) * NH + n0 + c4 * 4]);
            *reinterpret_cast<float4*>(&Bs[row][c4 * 4]) = v;
        }
        __syncthreads();
        #pragma unroll
        for (int kk = 0; kk < 64; ++kk) {
            float4 av = *reinterpret_cast<const float4*>(&As[kk][tm * 4]);
            float4 bv = *reinterpret_cast<const float4*>(&Bs[kk][tn * 4]);
            const float am[4] = {av.x, av.y, av.z, av.w};
            const float bn[4] = {bv.x, bv.y, bv.z, bv.w};
            #pragma unroll
            for (int i = 0; i < 4; ++i)
                #pragma unroll
                for (int j = 0; j < 4; ++j)
                    acc[i][j] += am[i] * bn[j];
        }
        __syncthreads();
    }
    float bias[4];
    #pragma unroll
    for (int j = 0; j < 4; ++j) bias[j] = bh[n0 + tn * 4 + j];
    #pragma unroll
    for (int i = 0; i < 4; ++i) {
        const int m = m0 + tm * 4 + i;
        ushort4 out;
        out.x = ftoh(acc[i][0] + bias[0]);
        out.y = ftoh(acc[i][1] + bias[1]);
        out.z = ftoh(acc[i][2] + bias[2]);
        out.w = ftoh(acc[i][3] + bias[3]);
        *reinterpret_cast<ushort4*>(&C[(size_t)m * NH + n0 + tn * 4]) = out;
    }
}

// ---------------- Phase 2: sequential recurrence (int8 dot4, 16 waves) ----------------
#define DOT16(HG, WQ, ACC)                 \
    ACC = sdot4((HG).x, (WQ).x, ACC);      \
    ACC = sdot4((HG).y, (WQ).y, ACC);      \
    ACC = sdot4((HG).z, (WQ).z, ACC);      \
    ACC = sdot4((HG).w, (WQ).w, ACC);

__global__ __launch_bounds__(1024)
void rnn_seq(const float* __restrict__ h0,    // [NB][NH]
             const u16* __restrict__ U,       // [NB*NT][NH] f16
             u16* __restrict__ H,             // [NB*NT][NH] f16 (out)
             const uint4* __restrict__ Wpk,   // int8 W, 16384 uint4 (L:8192, S:8192)
             const float* __restrict__ cbuf) {// per-col pre-scales [NH]
    const int b = blockIdx.x;
    const int tid = threadIdx.x;
    const int w = tid >> 6, l = tid & 63;
    const int kc = w & 7, ch = w >> 3;

    __shared__ __align__(16) uint4 Wl[8192];        // LDS-resident int8 W, 128 KiB
    __shared__ __align__(16) int part2[8][NH];      // int32 partials, 16 KiB
    __shared__ __align__(16) u32 h8[NH / 4];        // int8 h, 512 B

    // One-time: copy LDS W section (coalesced b128); load scale; quantize h0.
    #pragma unroll
    for (int j = 0; j < 8; ++j) Wl[j * 1024 + tid] = Wpk[j * 1024 + tid];

    float hreg = 0.f, cf_reg = 0.f;
    if (tid < NH) {
        hreg = h0[b * NH + tid];
        cf_reg = cbuf[tid];
        float qv = rintf(hreg * (127.f / S_H));
        qv = fminf(fmaxf(qv, -127.f), 127.f);
        reinterpret_cast<unsigned char*>(h8)[tid] = (unsigned char)((int)qv);
    }
    __syncthreads();

    const u16* __restrict__ Urow = U + (size_t)b * NT * NH + tid;
    u16* __restrict__ Hrow = H + (size_t)b * NT * NH + tid;
    const uint4* __restrict__ wls = Wl + (ch * 8 + kc) * 512 + l;                 // LDS W
    const uint4* __restrict__ wqs = Wpk + 8192 + (size_t)(ch * 8 + kc) * 512 + l; // stream
    const uint4* __restrict__ hqb = reinterpret_cast<const uint4*>(h8) + kc * 4;

    // Primed: LDS q0 pair + stream groups g0/g1 (stream W is step-invariant).
    uint4 dA0 = wls[0], dA1 = wls[64];
    uint4 dB0, dB1;
    uint4 sA0 = wqs[0],   sA1 = wqs[64];
    uint4 sB0 = wqs[128], sB1 = wqs[192];

    u16 ub_cur = (tid < NH) ? Urow[0] : (u16)0;

    #pragma unroll 1
    for (int t = 0; t < NT; ++t) {
        u16 ub_nxt = 0;
        if (tid < NH) ub_nxt = Urow[(size_t)(t + 1) * NH];   // safe: H follows U in ws

        uint4 hA = hqb[0], hB = hqb[1];
        int acc0 = 0, acc1 = 0, acc2 = 0, acc3 = 0;   // cols +0,+1 (LDS), +2,+3 (stream)

        // G0 (k-quad q=0)
        dB0 = wls[2 * 64]; dB1 = wls[3 * 64];
        DOT16(hA, dA0, acc0) DOT16(hA, dA1, acc1) DOT16(hA, sA0, acc2) DOT16(hA, sA1, acc3)
        hA = hqb[2];
        sA0 = wqs[256]; sA1 = wqs[320];      // g2
        // G1 (q=1)
        dA0 = wls[4 * 64]; dA1 = wls[5 * 64];
        DOT16(hB, dB0, acc0) DOT16(hB, dB1, acc1) DOT16(hB, sB0, acc2) DOT16(hB, sB1, acc3)
        hB = hqb[3];
        sB0 = wqs[384]; sB1 = wqs[448];      // g3
        // G2 (q=2)
        dB0 = wls[6 * 64]; dB1 = wls[7 * 64];
        DOT16(hA, dA0, acc0) DOT16(hA, dA1, acc1) DOT16(hA, sA0, acc2) DOT16(hA, sA1, acc3)
        sA0 = wqs[0]; sA1 = wqs[64];         // g0 (next step)
        // G3 (q=3)
        dA0 = wls[0]; dA1 = wls[64];         // q0 (next step)
        DOT16(hB, dB0, acc0) DOT16(hB, dB1, acc1) DOT16(hB, sB0, acc2) DOT16(hB, sB1, acc3)
        sB0 = wqs[128]; sB1 = wqs[192];      // g1 (next step)

        // Partials: cols ch*256+4l+0..3 -> one int4 store (dense, conflict-free).
        int4 pw; pw.x = acc0; pw.y = acc1; pw.z = acc2; pw.w = acc3;
        *reinterpret_cast<int4*>(&part2[kc][ch * 256 + 4 * l]) = pw;
        __syncthreads();

        // Update h[tid]: exact int32 8-way k-chunk reduction (lanes consecutive, free).
        if (tid < NH) {
            const int isum = ((part2[0][tid] + part2[1][tid]) + (part2[2][tid] + part2[3][tid]))
                           + ((part2[4][tid] + part2[5][tid]) + (part2[6][tid] + part2[7][tid]));
            const float pre = (float)isum * cf_reg + htof(ub_cur);
            const float e = __expf(2.f * pre);
            hreg = 0.9f * hreg + 0.1f * (1.f - 2.f / (e + 1.f));
            Hrow[(size_t)t * NH] = ftoh(hreg);
            float qv = rintf(hreg * (127.f / S_H));
            qv = fminf(fmaxf(qv, -127.f), 127.f);
            reinterpret_cast<unsigned char*>(h8)[tid] = (unsigned char)((int)qv);
        }
        ub_cur = ub_nxt;
        __syncthreads();
    }
}

// ---------------- Phase 3: Y[m][n] = H[m][:] @ W_hy[:,n] + b_y[n]  (fp32 out) ----------------
__global__ __launch_bounds__(256) void y_gemm(
        const u16* __restrict__ H,      // [M][NH] f16
        const float* __restrict__ Why,  // [NH][NO]
        const float* __restrict__ by,   // [NO]
        float* __restrict__ Y) {        // [M][NO]
    const int m0 = blockIdx.x * 64;
    const int tid = threadIdx.x;
    const int tn = tid & 15, tm = tid >> 4;
    __shared__ float As[64][68];    // [k][m]
    __shared__ float Bs[64][132];   // [k][n]
    float acc[4][8] = {};
    for (int k0 = 0; k0 < NH; k0 += 64) {
        #pragma unroll
        for (int p = 0; p < 4; ++p) {
            const int idx = tid + p * 256;
            const int r = idx >> 4;
            const int c4 = idx & 15;
            ushort4 v = *reinterpret_cast<const ushort4*>(&H[(size_t)(m0 + r) * NH + k0 + c4 * 4]);
            As[c4 * 4 + 0][r] = htof(v.x); As[c4 * 4 + 1][r] = htof(v.y);
            As[c4 * 4 + 2][r] = htof(v.z); As[c4 * 4 + 3][r] = htof(v.w);
        }
        #pragma unroll
        for (int p = 0; p < 8; ++p) {
            const int idx = tid + p * 256;
            const int r = idx >> 5;
            const int c4 = idx & 31;
            float4 v = *reinterpret_cast<const float4*>(&Why[(size_t)(k0 + r) * NO + c4 * 4]);
            *reinterpret_cast<float4*>(&Bs[r][c4 * 4]) = v;
        }
        __syncthreads();
        #pragma unroll
        for (int kk = 0; kk < 64; ++kk) {
            float4 av = *reinterpret_cast<const float4*>(&As[kk][tm * 4]);
            float4 b0 = *reinterpret_cast<const float4*>(&Bs[kk][tn * 8]);
            float4 b1 = *reinterpret_cast<const float4*>(&Bs[kk][tn * 8 + 4]);
            const float am[4] = {av.x, av.y, av.z, av.w};
            const float bn[8] = {b0.x, b0.y, b0.z, b0.w, b1.x, b1.y, b1.z, b1.w};
            #pragma unroll
            for (int i = 0; i < 4; ++i)
                #pragma unroll
                for (int j = 0; j < 8; ++j)
                    acc[i][j] += am[i] * bn[j];
        }
        __syncthreads();
    }
    float bias[8];
    #pragma unroll
    for (int j = 0; j < 8; ++j) bias[j] = by[tn * 8 + j];
    #pragma unroll
    for (int i = 0; i < 4; ++i) {
        const int m = m0 + tm * 4 + i;
        float4 o0, o1;
        o0.x = acc[i][0] + bias[0]; o0.y = acc[i][1] + bias[1];
        o0.z = acc[i][2] + bias[2]; o0.w = acc[i][3] + bias[3];
        o1.x = acc[i][4] + bias[4]; o1.y = acc[i][5] + bias[5];
        o1.z = acc[i][6] + bias[6]; o1.w = acc[i][7] + bias[7];
        *reinterpret_cast<float4*>(&Y[(size_t)m * NO + tn * 8]) = o0;
        *reinterpret_cast<float4*>(&Y[(size_t)m * NO + tn * 8 + 4]) = o1;
    }
}

extern "C" void kernel_launch(void* const* d_in, const int* in_sizes, int n_in,
                              void* d_out, int out_size, void* d_ws, size_t ws_size,
                              hipStream_t stream) {
    const float* u   = (const float*)d_in[0];   // [64][2048][128]
    const float* h0  = (const float*)d_in[1];   // [64][512]
    const float* Wuh = (const float*)d_in[2];   // [128][512]
    const float* Whh = (const float*)d_in[3];   // [512][512]
    const float* Why = (const float*)d_in[4];   // [512][128]
    const float* bh  = (const float*)d_in[5];   // [512]
    const float* by  = (const float*)d_in[6];   // [128]
    float* y = (float*)d_out;                   // [64][2048][128] fp32

    u16* Uws = (u16*)d_ws;                       // 128 MiB
    u16* Hws = Uws + (size_t)NB * NT * NH;       // 128 MiB
    // Scratch in d_out (dead until y_gemm overwrites all of it last):
    uint4* Wpk  = (uint4*)d_out;                 // 256 KiB int8 W
    float* sbuf = (float*)(Wpk + 16384);         // 2 KiB quant steps
    float* cbuf = sbuf + NH;                     // 2 KiB pre-scales
    (void)in_sizes; (void)n_in; (void)out_size; (void)ws_size;

    wscale<<<dim3(8), 256, 0, stream>>>(Whh, sbuf, cbuf);
    wpack<<<dim3(64), 256, 0, stream>>>(Whh, sbuf, Wpk);
    u_gemm<<<dim3(NH / 64, (NB * NT) / 64), 256, 0, stream>>>(u, Wuh, bh, Uws);
    rnn_seq<<<dim3(NB), 1024, 0, stream>>>(h0, Uws, Hws, Wpk, cbuf);
    y_gemm<<<dim3((NB * NT) / 64), 256, 0, stream>>>(Hws, Why, by, y);
}

// Round 12
// 2228.118 us; speedup vs baseline: 2.3199x; 1.0212x over previous
//
#include <hip/hip_runtime.h>
#include <cmath>

// Leaky RNN:  h_t = 0.9 h_{t-1} + 0.1 tanh(h W_hh + u_t W_uh + b_h);  y_t = h_t W_hy + b_y
// B=64, T=2048, N_in=128, N_h=512, N_out=128.
//
// Phase 2 (critical path): one WG per batch row, 1024 threads = 16 waves (4/SIMD).
// Round-11 was LDS-pipe-bound delivering W (128 KB/step from LDS + 128 KB from L2).
// At int8 the per-thread W slice is only 16 uint4 = 64 VGPR -> W_hh is now FULLY
// REGISTER-RESIDENT (demand ~90 < the 128-VGPR cap; round-11 base was ~20 + quads).
// No LDS W, no L2 W stream.  Wave (kc=w&7, ch=w>>3); lane l owns cols ch*256+4l+0..3,
// k in [64kc, 64kc+64).  Exact int32 accumulation via v_dot4_i32_i8; per-column scales;
// h int8 (fixed S_H) in 512-B LDS; f32 recurrence state.  Partials int32 [8][512]
// (int4 writes / strided reads, conflict-free - measured 0).  2 barriers/step.
//
// ws: U (f16 [B*T][512], 128 MiB) | H (f16 [B*T][512], 128 MiB).
// Wpk (256 KiB int8 W) + scale bufs live in d_out (dead until y_gemm runs last).

#define NB 64
#define NT 2048
#define NI 128
#define NH 512
#define NO 128
#define S_H 4.6f

typedef unsigned short u16;
typedef unsigned int u32;
typedef _Float16 half2_t __attribute__((ext_vector_type(2)));

__device__ __forceinline__ int sdot4(u32 a, u32 b, int c) {
#if __has_builtin(__builtin_amdgcn_sdot4)
    return __builtin_amdgcn_sdot4(a, b, c, false);
#else
    int r = c;
    r += (int)(signed char)(a) * (int)(signed char)(b);
    r += (int)(signed char)(a >> 8) * (int)(signed char)(b >> 8);
    r += (int)(signed char)(a >> 16) * (int)(signed char)(b >> 16);
    r += (int)(signed char)(a >> 24) * (int)(signed char)(b >> 24);
    return r;
#endif
}

__device__ __forceinline__ u16 ftoh(float x) { return __builtin_bit_cast(u16, (_Float16)x); }
__device__ __forceinline__ float htof(u16 x) { return (float)__builtin_bit_cast(_Float16, x); }

// ---------------- Phase -1: per-column |max| of W_hh -> scales ----------------
__global__ __launch_bounds__(256) void wscale(const float* __restrict__ Whh,
                                              float* __restrict__ sbuf,
                                              float* __restrict__ cbuf) {
    const int n0 = blockIdx.x * 64;
    const int r = threadIdx.x >> 6, c = threadIdx.x & 63;
    const int n = n0 + c;
    float m = 0.f;
    for (int k = r; k < NH; k += 4) m = fmaxf(m, fabsf(Whh[(size_t)k * NH + n]));
    __shared__ float red[4][64];
    red[r][c] = m;
    __syncthreads();
    if (r == 0) {
        m = fmaxf(fmaxf(red[0][c], red[1][c]), fmaxf(red[2][c], red[3][c]));
        m = fmaxf(m, 1e-8f);
        sbuf[n] = m * (1.f / 127.f);
        cbuf[n] = S_H * m * (1.f / 16129.f);
    }
}

// ---------------- Phase 0: pack W_hh to int8, consumer order ----------------
// idx = sec*8192 + (((ch*8+kc)*4+q)*2+ci)*64 + l.  sec 0: cols ch*256+4l+ci;
// sec 1: cols ch*256+4l+2+ci.  kb = kc*64 + q*16; uint4 = 16 int8, word j = k kb+4j..+3.
__global__ __launch_bounds__(256) void wpack(const float* __restrict__ Whh,
                                             const float* __restrict__ sbuf,
                                             uint4* __restrict__ Wpk) {
    const int idx = blockIdx.x * 256 + threadIdx.x;   // 0..16383
    const int sec = idx >> 13;
    const int r = idx & 8191;
    const int l = r & 63;
    const int ci = (r >> 6) & 1;
    const int q = (r >> 7) & 3;
    const int kc = (r >> 9) & 7;
    const int ch = r >> 12;
    const int col = ch * 256 + 4 * l + (sec ? 2 : 0) + ci;
    const int kb = kc * 64 + q * 16;
    const float inv = 1.f / sbuf[col];
    u32 words[4];
    #pragma unroll
    for (int wd = 0; wd < 4; ++wd) {
        u32 acc = 0;
        #pragma unroll
        for (int j = 0; j < 4; ++j) {
            const int k = kb + wd * 4 + j;
            float qv = rintf(Whh[(size_t)k * NH + col] * inv);
            qv = fminf(fmaxf(qv, -127.f), 127.f);
            acc |= ((u32)((int)qv & 0xFF)) << (8 * j);
        }
        words[wd] = acc;
    }
    uint4 o; o.x = words[0]; o.y = words[1]; o.z = words[2]; o.w = words[3];
    Wpk[idx] = o;
}

// ---------------- Phase 1: U[m][n] = u[m][:] @ W_uh[:,n] + b_h[n]  (f16 out) ----------------
__global__ __launch_bounds__(256) void u_gemm(
        const float* __restrict__ A,    // u  [M][NI]
        const float* __restrict__ Bw,   // W_uh [NI][NH]
        const float* __restrict__ bh,   // [NH]
        u16* __restrict__ C) {          // U [M][NH] f16
    const int n0 = blockIdx.x * 64;
    const int m0 = blockIdx.y * 64;
    const int tid = threadIdx.x;
    const int tn = tid & 15, tm = tid >> 4;
    __shared__ float As[64][68];   // [k][m]
    __shared__ float Bs[64][68];   // [k][n]
    float acc[4][4] = {};
    for (int k0 = 0; k0 < NI; k0 += 64) {
        const int r = tid >> 4, c4 = tid & 15;
        #pragma unroll
        for (int p = 0; p < 4; ++p) {
            const int row = r + p * 16;
            float4 v = *reinterpret_cast<const float4*>(&A[(size_t)(m0 + row) * NI + k0 + c4 * 4]);
            As[c4 * 4 + 0][row] = v.x; As[c4 * 4 + 1][row] = v.y;
            As[c4 * 4 + 2][row] = v.z; As[c4 * 4 + 3][row] = v.w;
        }
        #pragma unroll
        for (int p = 0; p < 4; ++p) {
            const int row = r + p * 16;
            float4 v = *reinterpret_cast<const float4*>(&Bw[(size_t)(k0 + row) * NH + n0 + c4 * 4]);
            *reinterpret_cast<float4*>(&Bs[row][c4 * 4]) = v;
        }
        __syncthreads();
        #pragma unroll
        for (int kk = 0; kk < 64; ++kk) {
            float4 av = *reinterpret_cast<const float4*>(&As[kk][tm * 4]);
            float4 bv = *reinterpret_cast<const float4*>(&Bs[kk][tn * 4]);
            const float am[4] = {av.x, av.y, av.z, av.w};
            const float bn[4] = {bv.x, bv.y, bv.z, bv.w};
            #pragma unroll
            for (int i = 0; i < 4; ++i)
                #pragma unroll
                for (int j = 0; j < 4; ++j)
                    acc[i][j] += am[i] * bn[j];
        }
        __syncthreads();
    }
    float bias[4];
    #pragma unroll
    for (int j = 0; j < 4; ++j) bias[j] = bh[n0 + tn * 4 + j];
    #pragma unroll
    for (int i = 0; i < 4; ++i) {
        const int m = m0 + tm * 4 + i;
        ushort4 out;
        out.x = ftoh(acc[i][0] + bias[0]);
        out.y = ftoh(acc[i][1] + bias[1]);
        out.z = ftoh(acc[i][2] + bias[2]);
        out.w = ftoh(acc[i][3] + bias[3]);
        *reinterpret_cast<ushort4*>(&C[(size_t)m * NH + n0 + tn * 4]) = out;
    }
}

// ---------------- Phase 2: sequential recurrence (int8 dot4, W in registers) ----------------
#define DOT16(HG, WQ, ACC)                 \
    ACC = sdot4((HG).x, (WQ).x, ACC);      \
    ACC = sdot4((HG).y, (WQ).y, ACC);      \
    ACC = sdot4((HG).z, (WQ).z, ACC);      \
    ACC = sdot4((HG).w, (WQ).w, ACC);

__global__ __launch_bounds__(1024)
void rnn_seq(const float* __restrict__ h0,    // [NB][NH]
             const u16* __restrict__ U,       // [NB*NT][NH] f16
             u16* __restrict__ H,             // [NB*NT][NH] f16 (out)
             const uint4* __restrict__ Wpk,   // int8 W, 16384 uint4 (sec0:8192, sec1:8192)
             const float* __restrict__ cbuf) {// per-col pre-scales [NH]
    const int b = blockIdx.x;
    const int tid = threadIdx.x;
    const int w = tid >> 6, l = tid & 63;
    const int kc = w & 7, ch = w >> 3;

    __shared__ __align__(16) int part2[8][NH];      // int32 partials, 16 KiB
    __shared__ __align__(16) u32 h8[NH / 4];        // int8 h, 512 B

    // W_hh fully register-resident: 16 named uint4 (cols ch*256+4l+0..3 x k-quads 0..3).
    // One-time coalesced b128 loads; step-invariant thereafter.
    const uint4* __restrict__ w0b = Wpk + (size_t)(ch * 8 + kc) * 512 + l;         // cols 0,1
    const uint4* __restrict__ w1b = Wpk + 8192 + (size_t)(ch * 8 + kc) * 512 + l;  // cols 2,3
    uint4 s0_0 = w0b[0],   s0_1 = w0b[64],  s0_2 = w1b[0],   s0_3 = w1b[64];   // q0
    uint4 s1_0 = w0b[128], s1_1 = w0b[192], s1_2 = w1b[128], s1_3 = w1b[192];  // q1
    uint4 s2_0 = w0b[256], s2_1 = w0b[320], s2_2 = w1b[256], s2_3 = w1b[320];  // q2
    uint4 s3_0 = w0b[384], s3_1 = w0b[448], s3_2 = w1b[384], s3_3 = w1b[448];  // q3

    float hreg = 0.f, cf_reg = 0.f;
    if (tid < NH) {
        hreg = h0[b * NH + tid];
        cf_reg = cbuf[tid];
        float qv = rintf(hreg * (127.f / S_H));
        qv = fminf(fmaxf(qv, -127.f), 127.f);
        reinterpret_cast<unsigned char*>(h8)[tid] = (unsigned char)((int)qv);
    }
    __syncthreads();

    const u16* __restrict__ Urow = U + (size_t)b * NT * NH + tid;
    u16* __restrict__ Hrow = H + (size_t)b * NT * NH + tid;
    const uint4* __restrict__ hqb = reinterpret_cast<const uint4*>(h8) + kc * 4;

    u16 ub_cur = (tid < NH) ? Urow[0] : (u16)0;

    #pragma unroll 1
    for (int t = 0; t < NT; ++t) {
        u16 ub_nxt = 0;
        if (tid < NH) ub_nxt = Urow[(size_t)(t + 1) * NH];   // safe: H follows U in ws

        uint4 hA = hqb[0], hB = hqb[1];
        int acc0 = 0, acc1 = 0, acc2 = 0, acc3 = 0;

        // q0
        DOT16(hA, s0_0, acc0) DOT16(hA, s0_1, acc1) DOT16(hA, s0_2, acc2) DOT16(hA, s0_3, acc3)
        hA = hqb[2];
        // q1
        DOT16(hB, s1_0, acc0) DOT16(hB, s1_1, acc1) DOT16(hB, s1_2, acc2) DOT16(hB, s1_3, acc3)
        hB = hqb[3];
        // q2
        DOT16(hA, s2_0, acc0) DOT16(hA, s2_1, acc1) DOT16(hA, s2_2, acc2) DOT16(hA, s2_3, acc3)
        // q3
        DOT16(hB, s3_0, acc0) DOT16(hB, s3_1, acc1) DOT16(hB, s3_2, acc2) DOT16(hB, s3_3, acc3)

        // Partials: cols ch*256+4l+0..3 -> one int4 store (dense, conflict-free).
        int4 pw; pw.x = acc0; pw.y = acc1; pw.z = acc2; pw.w = acc3;
        *reinterpret_cast<int4*>(&part2[kc][ch * 256 + 4 * l]) = pw;
        __syncthreads();

        // Update h[tid]: exact int32 8-way k-chunk reduction (lanes consecutive, free).
        if (tid < NH) {
            const int isum = ((part2[0][tid] + part2[1][tid]) + (part2[2][tid] + part2[3][tid]))
                           + ((part2[4][tid] + part2[5][tid]) + (part2[6][tid] + part2[7][tid]));
            const float pre = (float)isum * cf_reg + htof(ub_cur);
            const float e = __expf(2.f * pre);
            hreg = 0.9f * hreg + 0.1f * (1.f - 2.f / (e + 1.f));
            Hrow[(size_t)t * NH] = ftoh(hreg);
            float qv = rintf(hreg * (127.f / S_H));
            qv = fminf(fmaxf(qv, -127.f), 127.f);
            reinterpret_cast<unsigned char*>(h8)[tid] = (unsigned char)((int)qv);
        }
        ub_cur = ub_nxt;
        __syncthreads();
    }
}

// ---------------- Phase 3: Y[m][n] = H[m][:] @ W_hy[:,n] + b_y[n]  (fp32 out) ----------------
__global__ __launch_bounds__(256) void y_gemm(
        const u16* __restrict__ H,      // [M][NH] f16
        const float* __restrict__ Why,  // [NH][NO]
        const float* __restrict__ by,   // [NO]
        float* __restrict__ Y) {        // [M][NO]
    const int m0 = blockIdx.x * 64;
    const int tid = threadIdx.x;
    const int tn = tid & 15, tm = tid >> 4;
    __shared__ float As[64][68];    // [k][m]
    __shared__ float Bs[64][132];   // [k][n]
    float acc[4][8] = {};
    for (int k0 = 0; k0 < NH; k0 += 64) {
        #pragma unroll
        for (int p = 0; p < 4; ++p) {
            const int idx = tid + p * 256;
            const int r = idx >> 4;
            const int c4 = idx & 15;
            ushort4 v = *reinterpret_cast<const ushort4*>(&H[(size_t)(m0 + r) * NH + k0 + c4 * 4]);
            As[c4 * 4 + 0][r] = htof(v.x); As[c4 * 4 + 1][r] = htof(v.y);
            As[c4 * 4 + 2][r] = htof(v.z); As[c4 * 4 + 3][r] = htof(v.w);
        }
        #pragma unroll
        for (int p = 0; p < 8; ++p) {
            const int idx = tid + p * 256;
            const int r = idx >> 5;
            const int c4 = idx & 31;
            float4 v = *reinterpret_cast<const float4*>(&Why[(size_t)(k0 + r) * NO + c4 * 4]);
            *reinterpret_cast<float4*>(&Bs[r][c4 * 4]) = v;
        }
        __syncthreads();
        #pragma unroll
        for (int kk = 0; kk < 64; ++kk) {
            float4 av = *reinterpret_cast<const float4*>(&As[kk][tm * 4]);
            float4 b0 = *reinterpret_cast<const float4*>(&Bs[kk][tn * 8]);
            float4 b1 = *reinterpret_cast<const float4*>(&Bs[kk][tn * 8 + 4]);
            const float am[4] = {av.x, av.y, av.z, av.w};
            const float bn[8] = {b0.x, b0.y, b0.z, b0.w, b1.x, b1.y, b1.z, b1.w};
            #pragma unroll
            for (int i = 0; i < 4; ++i)
                #pragma unroll
                for (int j = 0; j < 8; ++j)
                    acc[i][j] += am[i] * bn[j];
        }
        __syncthreads();
    }
    float bias[8];
    #pragma unroll
    for (int j = 0; j < 8; ++j) bias[j] = by[tn * 8 + j];
    #pragma unroll
    for (int i = 0; i < 4; ++i) {
        const int m = m0 + tm * 4 + i;
        float4 o0, o1;
        o0.x = acc[i][0] + bias[0]; o0.y = acc[i][1] + bias[1];
        o0.z = acc[i][2] + bias[2]; o0.w = acc[i][3] + bias[3];
        o1.x = acc[i][4] + bias[4]; o1.y = acc[i][5] + bias[5];
        o1.z = acc[i][6] + bias[6]; o1.w = acc[i][7] + bias[7];
        *reinterpret_cast<float4*>(&Y[(size_t)m * NO + tn * 8]) = o0;
        *reinterpret_cast<float4*>(&Y[(size_t)m * NO + tn * 8 + 4]) = o1;
    }
}

extern "C" void kernel_launch(void* const* d_in, const int* in_sizes, int n_in,
                              void* d_out, int out_size, void* d_ws, size_t ws_size,
                              hipStream_t stream) {
    const float* u   = (const float*)d_in[0];   // [64][2048][128]
    const float* h0  = (const float*)d_in[1];   // [64][512]
    const float* Wuh = (const float*)d_in[2];   // [128][512]
    const float* Whh = (const float*)d_in[3];   // [512][512]
    const float* Why = (const float*)d_in[4];   // [512][128]
    const float* bh  = (const float*)d_in[5];   // [512]
    const float* by  = (const float*)d_in[6];   // [128]
    float* y = (float*)d_out;                   // [64][2048][128] fp32

    u16* Uws = (u16*)d_ws;                       // 128 MiB
    u16* Hws = Uws + (size_t)NB * NT * NH;       // 128 MiB
    // Scratch in d_out (dead until y_gemm overwrites all of it last):
    uint4* Wpk  = (uint4*)d_out;                 // 256 KiB int8 W
    float* sbuf = (float*)(Wpk + 16384);         // 2 KiB quant steps
    float* cbuf = sbuf + NH;                     // 2 KiB pre-scales
    (void)in_sizes; (void)n_in; (void)out_size; (void)ws_size;

    wscale<<<dim3(8), 256, 0, stream>>>(Whh, sbuf, cbuf);
    wpack<<<dim3(64), 256, 0, stream>>>(Whh, sbuf, Wpk);
    u_gemm<<<dim3(NH / 64, (NB * NT) / 64), 256, 0, stream>>>(u, Wuh, bh, Uws);
    rnn_seq<<<dim3(NB), 1024, 0, stream>>>(h0, Uws, Hws, Wpk, cbuf);
    y_gemm<<<dim3((NB * NT) / 64), 256, 0, stream>>>(Hws, Why, by, y);
}